// Round 6
// baseline (1980.272 us; speedup 1.0000x reference)
//
#include <hip/hip_runtime.h>

// HWTV: ADMM TV solver, 124 independent 128x128 images, 20 iterations.
// One workgroup per image; whole iteration loop in-kernel.
// Round 6: R2-R5 proved the backend pins this kernel at 64 VGPRs regardless
// of __launch_bounds__ / amdgpu_waves_per_eu hints -> any >64-float live set
// spills to scratch (1.4 GB HBM traffic). Fix: make the kernel FIT in 64.
//   - bh = mu2*Uh+G21, bv = mu2*Uv+G22: registers (32 floats, the only state
//     that must survive the FFT section).
//   - a = mu1*X+G1 and g1: d_ws (coalesced, L2-resident: 2 MB/XCD < 4 MB L2;
//     one read + one write site per iteration each).
// FFT unchanged: radix-2 DIF forward (bit-rev out) -> pointwise solve with
// bit-rev denom table -> radix-2 DIT inverse (bit-rev in), 1/N^2 folded in.

#define NPIX   16384
#define NSIDE  128
#define NIMG   124
#define NT     1024
#define PXT    16          // pixels per thread
#define N_ITE  20
#define LAM_F  0.1f
#define RHO_F  1.05f
#define PI_F   3.14159265358979323846f

__device__ __forceinline__ void bfly_fwd(float2& A, float2& B, float wr, float wi) {
    float ar = A.x, ai = A.y, br = B.x, bi = B.y;
    A.x = ar + br; A.y = ai + bi;
    float tr = ar - br, ti = ai - bi;
    B.x = tr * wr - ti * wi;
    B.y = tr * wi + ti * wr;
}

__device__ __forceinline__ void bfly_inv(float2& A, float2& B, float wr, float wi) {
    // b * conj(w), then a+b / a-b
    float ar = A.x, ai = A.y, br = B.x, bi = B.y;
    float pr = br * wr + bi * wi;
    float pi = bi * wr - br * wi;
    A.x = ar + pr; A.y = ai + pi;
    B.x = ar - pr; B.y = ai - pi;
}

__global__ __launch_bounds__(NT) void hwtv_kernel(
    const float* __restrict__ Yg,
    const float* __restrict__ Wg,
    float* __restrict__ outg,
    float* __restrict__ wsg)
{
    extern __shared__ char smem[];
    float2* C  = (float2*)smem;                            // 16384 complex (128 KB)
    float2* TW = (float2*)(smem + (size_t)NPIX * 8);       // 64 twiddles W_128^k
    float*  D1 = (float*)(smem + (size_t)NPIX * 8 + 64*8); // 128: 4sin^2(pi*bitrev7(i)/128)

    const int tid = threadIdx.x;
    const size_t base  = (size_t)blockIdx.x * NPIX;
    const float* Y  = Yg + base;
    const float* Wt = Wg + base;
    float* out = outg + base;
    const size_t plane = (size_t)NIMG * NPIX;
    float* ag  = wsg + base;            // a = mu1*X + G1
    float* g1g = wsg + plane + base;    // G1

    // ---- one-time tables + Z0 = Y into LDS + ws init ----
    if (tid < 64) {
        float ang = -2.0f * PI_F * (float)tid / 128.0f;
        TW[tid] = make_float2(cosf(ang), sinf(ang));
    }
    if (tid < 128) {
        int br = (int)(__brev((unsigned)tid) >> 25);       // bitrev7
        float s = sinf(PI_F * (float)br / 128.0f);
        D1[tid] = 4.0f * s * s;
    }
    float bh[PXT], bv[PXT];   // the ONLY persistent register state (32 VGPRs)
    #pragma unroll
    for (int k = 0; k < PXT; ++k) {
        int p = tid + k * NT;
        float y = Y[p];
        C[p] = make_float2(y, 0.0f);     // Z0 = Y
        ag[p]  = 0.1f * y;               // mu1*X0 + G1_0 = mu1*Y
        g1g[p] = 0.0f;
        bh[k] = 0.0f;
        bv[k] = 0.0f;
    }
    __syncthreads();

    float mu1 = 0.1f, mu2 = 0.1f;

    for (int it = 0; it < N_ITE; ++it) {
        const float mu2p   = mu2 * (1.0f / RHO_F);  // previous iteration's mu2
        const float inv_m2 = 1.0f / mu2;
        const float thr    = LAM_F * inv_m2;

        // ---- P1: shrink; bh_new = mu2*Uh + G21, bv_new = mu2*Uv + G22 ----
        // Z (current) in C[].x; G21 = bh_old - mu2_prev*DhZ (DhZ of current Z).
        #pragma unroll
        for (int k = 0; k < PXT; ++k) {
            int p    = tid + k * NT;
            int col  = p & (NSIDE - 1);
            int rowb = p & ~(NSIDE - 1);
            float z  = C[p].x;
            float zl = C[rowb | ((col + NSIDE - 1) & (NSIDE - 1))].x;
            float zu = C[(p + NPIX - NSIDE) & (NPIX - 1)].x;
            float dhz = z - zl;
            float dvz = z - zu;
            float g21 = (it == 0) ? 0.0f : fmaf(-mu2p, dhz, bh[k]);
            float g22 = (it == 0) ? 0.0f : fmaf(-mu2p, dvz, bv[k]);
            float ah = dhz - g21 * inv_m2;
            float av = dvz - g22 * inv_m2;
            float uh = copysignf(fmaxf(fabsf(ah) - thr, 0.0f), ah);
            float uv = copysignf(fmaxf(fabsf(av) - thr, 0.0f), av);
            bh[k] = fmaf(mu2, uh, g21);
            bv[k] = fmaf(mu2, uv, g22);
        }
        __syncthreads();          // all Z reads done before overwriting C

        // ---- P2: stage (bh, bv) in C for neighbor exchange ----
        #pragma unroll
        for (int k = 0; k < PXT; ++k) {
            int p = tid + k * NT;
            C[p] = make_float2(bh[k], bv[k]);
        }
        __syncthreads();

        // ---- P3: numerator = a + Dh^T bh + Dv^T bv (a streamed from L2) ----
        float numv[PXT];
        #pragma unroll
        for (int k = 0; k < PXT; ++k) {
            int p    = tid + k * NT;
            int col  = p & (NSIDE - 1);
            int rowb = p & ~(NSIDE - 1);
            float bhr = C[rowb | ((col + 1) & (NSIDE - 1))].x;
            float bvd = C[(p + NSIDE) & (NPIX - 1)].y;
            numv[k] = ag[p] + (bh[k] - bhr) + (bv[k] - bvd);
        }
        __syncthreads();          // all neighbor reads done before overwrite

        // ---- P4: C <- numerator (real) ----
        #pragma unroll
        for (int k = 0; k < PXT; ++k) {
            int p = tid + k * NT;
            C[p] = make_float2(numv[k], 0.0f);
        }
        __syncthreads();

        // ---- forward FFT over rows (DIF, natural in -> bit-rev out) ----
        for (int s = 0; s < 7; ++s) {
            const int len = 64 >> s;
            #pragma unroll 4
            for (int q = 0; q < 8; ++q) {
                int tau = tid + q * NT;            // 0..8191
                int t   = tau & 63;                // butterfly within row
                int org = (tau >> 6) << 7;         // row * 128
                int j   = t & (len - 1);
                int i0  = ((t ^ j) << 1) | j;
                float2 w = TW[j << s];
                float2 A = C[org + i0];
                float2 B = C[org + i0 + len];
                bfly_fwd(A, B, w.x, w.y);
                C[org + i0]       = A;
                C[org + i0 + len] = B;
            }
            __syncthreads();
        }
        // ---- forward FFT over cols (DIF) ----
        for (int s = 0; s < 7; ++s) {
            const int len = 64 >> s;
            #pragma unroll 4
            for (int q = 0; q < 8; ++q) {
                int tau = tid + q * NT;
                int c   = tau & (NSIDE - 1);
                int t   = tau >> 7;                // 0..63
                int j   = t & (len - 1);
                int i0  = ((t ^ j) << 1) | j;
                int b0  = i0 * NSIDE + c;
                float2 w = TW[j << s];
                float2 A = C[b0];
                float2 B = C[b0 + len * NSIDE];
                bfly_fwd(A, B, w.x, w.y);
                C[b0]               = A;
                C[b0 + len * NSIDE] = B;
            }
            __syncthreads();
        }

        // ---- pointwise Fourier solve (bit-rev indexed), 1/N^2 folded in ----
        {
            const float sc = 1.0f / (float)NPIX;
            #pragma unroll
            for (int k = 0; k < PXT; ++k) {
                int p = tid + k * NT;
                float den = mu1 + mu2 * (D1[p >> 7] + D1[p & (NSIDE - 1)]);
                float f = sc * __builtin_amdgcn_rcpf(den);
                float2 v = C[p];
                C[p] = make_float2(v.x * f, v.y * f);
            }
            __syncthreads();
        }

        // ---- inverse FFT over cols (DIT, bit-rev in -> natural out) ----
        for (int s = 0; s < 7; ++s) {
            const int len = 1 << s;
            #pragma unroll 4
            for (int q = 0; q < 8; ++q) {
                int tau = tid + q * NT;
                int c   = tau & (NSIDE - 1);
                int t   = tau >> 7;
                int j   = t & (len - 1);
                int i0  = ((t ^ j) << 1) | j;
                int b0  = i0 * NSIDE + c;
                float2 w = TW[j << (6 - s)];
                float2 A = C[b0];
                float2 B = C[b0 + len * NSIDE];
                bfly_inv(A, B, w.x, w.y);
                C[b0]               = A;
                C[b0 + len * NSIDE] = B;
            }
            __syncthreads();
        }
        // ---- inverse FFT over rows (DIT) ----
        for (int s = 0; s < 7; ++s) {
            const int len = 1 << s;
            #pragma unroll 4
            for (int q = 0; q < 8; ++q) {
                int tau = tid + q * NT;
                int t   = tau & 63;
                int org = (tau >> 6) << 7;
                int j   = t & (len - 1);
                int i0  = ((t ^ j) << 1) | j;
                float2 w = TW[j << (6 - s)];
                float2 A = C[org + i0];
                float2 B = C[org + i0 + len];
                bfly_inv(A, B, w.x, w.y);
                C[org + i0]       = A;
                C[org + i0 + len] = B;
            }
            __syncthreads();
        }

        // ---- Epilogue: X/G1/a update streamed through L2; Z stays in C ----
        const float mu1n = mu1 * RHO_F;
        if (it != N_ITE - 1) {
            #pragma unroll
            for (int k = 0; k < PXT; ++k) {
                int p = tid + k * NT;
                float z  = C[p].x;
                float g1 = g1g[p];
                float x  = fmaf(Wt[p], Y[p], fmaf(mu1, z, -g1)) *
                           __builtin_amdgcn_rcpf(Wt[p] + mu1);
                g1 = fmaf(mu1, x - z, g1);
                g1g[p] = g1;
                ag[p]  = fmaf(mu1n, x, g1);
            }
        } else {
            #pragma unroll
            for (int k = 0; k < PXT; ++k) {
                int p = tid + k * NT;
                out[p] = C[p].x;
            }
        }
        // no barrier needed: next P1 only reads C (covered by FFT's last
        // barrier); P2's writes are behind P1's barrier.

        mu1 *= RHO_F;
        mu2 *= RHO_F;
    }
}

extern "C" void kernel_launch(void* const* d_in, const int* in_sizes, int n_in,
                              void* d_out, int out_size, void* d_ws, size_t ws_size,
                              hipStream_t stream) {
    (void)in_sizes; (void)n_in; (void)out_size; (void)ws_size;
    const float* Y   = (const float*)d_in[0];
    const float* inW = (const float*)d_in[1];
    float* out = (float*)d_out;
    float* ws  = (float*)d_ws;   // needs >= 16.3 MB (a + g1 planes)

    const size_t smem_bytes = (size_t)NPIX * 8 + 64 * 8 + 128 * 4;  // 132096
    hipFuncSetAttribute((const void*)hwtv_kernel,
                        hipFuncAttributeMaxDynamicSharedMemorySize,
                        (int)smem_bytes);
    hipLaunchKernelGGL(hwtv_kernel, dim3(NIMG), dim3(NT), smem_bytes, stream,
                       Y, inW, out, ws);
}

// Round 7
// 1427.410 us; speedup vs baseline: 1.3873x; 1.3873x over previous
//
#include <hip/hip_runtime.h>

// HWTV: ADMM TV solver, 124 independent 128x128 images, 20 iterations.
// One workgroup per image; whole iteration loop in-kernel.
// Round 7: the backend pins this kernel at 64 VGPRs (proven R2-R6, immune to
// launch_bounds / waves_per_eu). Fit under 64 BY CONSTRUCTION:
//   - persistent regs: bh = mu2*Uh+G21, bv = mu2*Uv+G22 (32 VGPRs)
//   - FFT: hoist q-invariant butterfly indices (row: t=tid&63 const; col:
//     c=tid&127 const), unroll 2 -> ~16 transient regs
//   - P3 numerator in two 8-px chunks (peak 9 private floats) with a
//     pre-read of the row127->row0 wrap value
//   - a = mu1*X+G1 and g1 in d_ws (thread-private, coalesced; L2 set
//     Y+W+a+g1 = 3.9 MB/XCD <= 4 MB L2)
// FFT: radix-2 DIF fwd (bit-rev out) -> pointwise solve (bit-rev denom
// table) -> radix-2 DIT inv (bit-rev in); 1/N^2 folded into solve.

#define NPIX   16384
#define NSIDE  128
#define NIMG   124
#define NT     1024
#define PXT    16          // pixels per thread
#define N_ITE  20
#define LAM_F  0.1f
#define RHO_F  1.05f
#define PI_F   3.14159265358979323846f

__device__ __forceinline__ void bfly_fwd(float2& A, float2& B, float wr, float wi) {
    float ar = A.x, ai = A.y, br = B.x, bi = B.y;
    A.x = ar + br; A.y = ai + bi;
    float tr = ar - br, ti = ai - bi;
    B.x = tr * wr - ti * wi;
    B.y = tr * wi + ti * wr;
}

__device__ __forceinline__ void bfly_inv(float2& A, float2& B, float wr, float wi) {
    // b * conj(w), then a+b / a-b
    float ar = A.x, ai = A.y, br = B.x, bi = B.y;
    float pr = br * wr + bi * wi;
    float pi = bi * wr - br * wi;
    A.x = ar + pr; A.y = ai + pi;
    B.x = ar - pr; B.y = ai - pi;
}

__global__ __launch_bounds__(NT) void hwtv_kernel(
    const float* __restrict__ Yg,
    const float* __restrict__ Wg,
    float* __restrict__ outg,
    float* __restrict__ wsg)
{
    extern __shared__ char smem[];
    float2* C  = (float2*)smem;                            // 16384 complex (128 KB)
    float2* TW = (float2*)(smem + (size_t)NPIX * 8);       // 64 twiddles W_128^k
    float*  D1 = (float*)(smem + (size_t)NPIX * 8 + 64*8); // 128: 4sin^2(pi*bitrev7(i)/128)

    const int tid = threadIdx.x;
    const size_t base  = (size_t)blockIdx.x * NPIX;
    const float* Y  = Yg + base;
    const float* Wt = Wg + base;
    float* out = outg + base;
    const size_t plane = (size_t)NIMG * NPIX;
    float* ag  = wsg + base;            // a = mu1*X + G1 (thread-private use)
    float* g1g = wsg + plane + base;    // G1            (thread-private use)

    // ---- one-time tables + Z0 = Y into LDS + ws init ----
    if (tid < 64) {
        float ang = -2.0f * PI_F * (float)tid / 128.0f;
        TW[tid] = make_float2(cosf(ang), sinf(ang));
    }
    if (tid < 128) {
        int br = (int)(__brev((unsigned)tid) >> 25);       // bitrev7
        float s = sinf(PI_F * (float)br / 128.0f);
        D1[tid] = 4.0f * s * s;
    }
    float bh[PXT], bv[PXT];   // ONLY persistent register state (32 VGPRs)
    #pragma unroll
    for (int k = 0; k < PXT; ++k) {
        int p = tid + k * NT;
        float y = Y[p];
        C[p] = make_float2(y, 0.0f);     // Z0 = Y
        ag[p]  = 0.1f * y;               // mu1*X0 + G1_0 = mu1*Y
        g1g[p] = 0.0f;
        bh[k] = 0.0f;
        bv[k] = 0.0f;
    }
    __syncthreads();

    float mu1 = 0.1f, mu2 = 0.1f;

    for (int it = 0; it < N_ITE; ++it) {
        const float mu2p   = mu2 * (1.0f / RHO_F);  // previous iteration's mu2
        const float inv_m2 = 1.0f / mu2;
        const float thr    = LAM_F * inv_m2;

        // ---- P1: shrink; bh = mu2*Uh + G21, bv = mu2*Uv + G22 ----
        // Z (current) in C[].x; G21 = bh_old - mu2_prev*DhZ.
        #pragma unroll
        for (int k = 0; k < PXT; ++k) {
            int p    = tid + k * NT;
            int col  = p & (NSIDE - 1);
            int rowb = p & ~(NSIDE - 1);
            float z  = C[p].x;
            float zl = C[rowb | ((col + NSIDE - 1) & (NSIDE - 1))].x;
            float zu = C[(p + NPIX - NSIDE) & (NPIX - 1)].x;
            float dhz = z - zl;
            float dvz = z - zu;
            float g21 = (it == 0) ? 0.0f : fmaf(-mu2p, dhz, bh[k]);
            float g22 = (it == 0) ? 0.0f : fmaf(-mu2p, dvz, bv[k]);
            float ah = dhz - g21 * inv_m2;
            float av = dvz - g22 * inv_m2;
            float uh = copysignf(fmaxf(fabsf(ah) - thr, 0.0f), ah);
            float uv = copysignf(fmaxf(fabsf(av) - thr, 0.0f), av);
            bh[k] = fmaf(mu2, uh, g21);
            bv[k] = fmaf(mu2, uv, g22);
        }
        __syncthreads();          // all Z reads done before overwriting C

        // ---- P2: stage (bh, bv) in C for neighbor exchange ----
        #pragma unroll
        for (int k = 0; k < PXT; ++k) {
            int p = tid + k * NT;
            C[p] = make_float2(bh[k], bv[k]);
        }
        __syncthreads();

        // ---- P3: numerator = a + Dh^T bh + Dv^T bv, in two 8-px chunks ----
        {
            float numv[8];
            // wrap pre-read: row 127 needs bv of row 0, which chunk A
            // overwrites. (Meaningful for tid>=896; harmless otherwise.)
            float bvd15 = C[((tid + 15 * NT) + NSIDE) & (NPIX - 1)].y;
            #pragma unroll
            for (int k = 0; k < 8; ++k) {          // rows 0..63: reads
                int p    = tid + k * NT;
                int col  = p & (NSIDE - 1);
                int rowb = p & ~(NSIDE - 1);
                float bhr = C[rowb | ((col + 1) & (NSIDE - 1))].x;
                float bvd = C[p + NSIDE].y;
                numv[k] = ag[p] + (bh[k] - bhr) + (bv[k] - bvd);
            }
            __syncthreads();
            #pragma unroll
            for (int k = 0; k < 8; ++k) {          // rows 0..63: writes
                int p = tid + k * NT;
                C[p] = make_float2(numv[k], 0.0f);
            }
            __syncthreads();
            #pragma unroll
            for (int k = 8; k < PXT; ++k) {        // rows 64..127: reads
                int p    = tid + k * NT;
                int col  = p & (NSIDE - 1);
                int rowb = p & ~(NSIDE - 1);
                float bhr = C[rowb | ((col + 1) & (NSIDE - 1))].x;
                float bvd = (p + NSIDE < NPIX) ? C[p + NSIDE].y : bvd15;
                numv[k - 8] = ag[p] + (bh[k] - bhr) + (bv[k] - bvd);
            }
            __syncthreads();
            #pragma unroll
            for (int k = 8; k < PXT; ++k) {        // rows 64..127: writes
                int p = tid + k * NT;
                C[p] = make_float2(numv[k - 8], 0.0f);
            }
            __syncthreads();
        }

        // ---- forward FFT over rows (DIF, natural in -> bit-rev out) ----
        {
            const int t  = tid & 63;     // q-invariant (1024 % 64 == 0)
            const int r0 = tid >> 6;     // 0..15
            for (int s = 0; s < 7; ++s) {
                const int len = 64 >> s;
                int j  = t & (len - 1);
                int i0 = ((t ^ j) << 1) | j;
                float2 w = TW[j << s];
                #pragma unroll 2
                for (int q = 0; q < 8; ++q) {
                    int org = (r0 + (q << 4)) << 7;       // row * 128
                    float2 A = C[org + i0];
                    float2 B = C[org + i0 + len];
                    bfly_fwd(A, B, w.x, w.y);
                    C[org + i0]       = A;
                    C[org + i0 + len] = B;
                }
                __syncthreads();
            }
        }
        // ---- forward FFT over cols (DIF) ----
        {
            const int c  = tid & (NSIDE - 1);  // q-invariant (1024 % 128 == 0)
            const int t0 = tid >> 7;           // 0..7
            for (int s = 0; s < 7; ++s) {
                const int len = 64 >> s;
                #pragma unroll 2
                for (int q = 0; q < 8; ++q) {
                    int t  = t0 + (q << 3);
                    int j  = t & (len - 1);
                    int i0 = ((t ^ j) << 1) | j;
                    float2 w = TW[j << s];
                    int b0 = (i0 << 7) + c;
                    float2 A = C[b0];
                    float2 B = C[b0 + (len << 7)];
                    bfly_fwd(A, B, w.x, w.y);
                    C[b0]              = A;
                    C[b0 + (len << 7)] = B;
                }
                __syncthreads();
            }
        }

        // ---- pointwise Fourier solve (bit-rev indexed), 1/N^2 folded in ----
        {
            const float sc = 1.0f / (float)NPIX;
            #pragma unroll 2
            for (int k = 0; k < PXT; ++k) {
                int p = tid + k * NT;
                float den = mu1 + mu2 * (D1[p >> 7] + D1[p & (NSIDE - 1)]);
                float f = sc * __builtin_amdgcn_rcpf(den);
                float2 v = C[p];
                C[p] = make_float2(v.x * f, v.y * f);
            }
            __syncthreads();
        }

        // ---- inverse FFT over cols (DIT, bit-rev in -> natural out) ----
        {
            const int c  = tid & (NSIDE - 1);
            const int t0 = tid >> 7;
            for (int s = 0; s < 7; ++s) {
                const int len = 1 << s;
                #pragma unroll 2
                for (int q = 0; q < 8; ++q) {
                    int t  = t0 + (q << 3);
                    int j  = t & (len - 1);
                    int i0 = ((t ^ j) << 1) | j;
                    float2 w = TW[j << (6 - s)];
                    int b0 = (i0 << 7) + c;
                    float2 A = C[b0];
                    float2 B = C[b0 + (len << 7)];
                    bfly_inv(A, B, w.x, w.y);
                    C[b0]              = A;
                    C[b0 + (len << 7)] = B;
                }
                __syncthreads();
            }
        }
        // ---- inverse FFT over rows (DIT) ----
        {
            const int t  = tid & 63;
            const int r0 = tid >> 6;
            for (int s = 0; s < 7; ++s) {
                const int len = 1 << s;
                int j  = t & (len - 1);
                int i0 = ((t ^ j) << 1) | j;
                float2 w = TW[j << (6 - s)];
                #pragma unroll 2
                for (int q = 0; q < 8; ++q) {
                    int org = (r0 + (q << 4)) << 7;
                    float2 A = C[org + i0];
                    float2 B = C[org + i0 + len];
                    bfly_inv(A, B, w.x, w.y);
                    C[org + i0]       = A;
                    C[org + i0 + len] = B;
                }
                __syncthreads();
            }
        }

        // ---- Epilogue: X/G1/a update via ws (no private arrays -> unroll 2)
        const float mu1n = mu1 * RHO_F;
        if (it != N_ITE - 1) {
            #pragma unroll 2
            for (int k = 0; k < PXT; ++k) {
                int p = tid + k * NT;
                float z   = C[p].x;
                float g1v = g1g[p];
                float w   = Wt[p];
                float x   = fmaf(w, Y[p], fmaf(mu1, z, -g1v)) *
                            __builtin_amdgcn_rcpf(w + mu1);
                g1v = fmaf(mu1, x - z, g1v);
                g1g[p] = g1v;
                ag[p]  = fmaf(mu1n, x, g1v);
            }
        } else {
            #pragma unroll 2
            for (int k = 0; k < PXT; ++k) {
                int p = tid + k * NT;
                out[p] = C[p].x;
            }
        }
        // no barrier: next P1 only reads C (covered by last FFT barrier).

        mu1 *= RHO_F;
        mu2 *= RHO_F;
    }
}

extern "C" void kernel_launch(void* const* d_in, const int* in_sizes, int n_in,
                              void* d_out, int out_size, void* d_ws, size_t ws_size,
                              hipStream_t stream) {
    (void)in_sizes; (void)n_in; (void)out_size; (void)ws_size;
    const float* Y   = (const float*)d_in[0];
    const float* inW = (const float*)d_in[1];
    float* out = (float*)d_out;
    float* ws  = (float*)d_ws;   // needs >= 16.3 MB (a + g1 planes)

    const size_t smem_bytes = (size_t)NPIX * 8 + 64 * 8 + 128 * 4;  // 132096
    hipFuncSetAttribute((const void*)hwtv_kernel,
                        hipFuncAttributeMaxDynamicSharedMemorySize,
                        (int)smem_bytes);
    hipLaunchKernelGGL(hwtv_kernel, dim3(NIMG), dim3(NT), smem_bytes, stream,
                       Y, inW, out, ws);
}

// Round 8
// 1307.737 us; speedup vs baseline: 1.5143x; 1.0915x over previous
//
#include <hip/hip_runtime.h>

// HWTV: ADMM TV solver, 124 independent 128x128 images, 20 iterations.
// One workgroup per image; whole iteration loop in-kernel.
// Round 8: radix-4 FFT. R7 proved spill is gone (traffic == 4 state planes);
// dominant cost is now the 28-stage radix-2 LDS FFT. Replace with mixed-radix
// per dim: R4(len=32) -> R4(8) -> R4(2) -> R2(1)  (4 stages/dim, 16 total).
// Scramble = mixed-radix digit reversal, folded into slot-indexed denom table.
// Inverse = mirrored DIT stages, conjugate twiddles. Row stride padded to 132
// float2 (row->row bank shift 8); final row R2 stage via conflict-free float4.
// Register budget (hard 64-VGPR wall, proven R2-R6): bh/bv persistent (32) +
// radix-4 transients (~18, unroll 1) + scalars ~ 58 < 64.
// State: bh=mu2*Uh+G21, bv=mu2*Uv+G22 in regs; a=mu1*X+G1, g1 in d_ws.

#define NPIX   16384
#define NSIDE  128
#define NIMG   124
#define NT     1024
#define PXT    16          // pixels per thread
#define N_ITE  20
#define LAM_F  0.1f
#define RHO_F  1.05f
#define PI_F   3.14159265358979323846f
#define ROWF2  132         // padded row stride in float2 (128 data + 4 pad)

__device__ __forceinline__ int IDX(int p) {       // logical pixel -> LDS slot
    return (p >> 7) * ROWF2 + (p & 127);
}
__device__ __forceinline__ float2 c_add(float2 a, float2 b) { return make_float2(a.x + b.x, a.y + b.y); }
__device__ __forceinline__ float2 c_sub(float2 a, float2 b) { return make_float2(a.x - b.x, a.y - b.y); }
__device__ __forceinline__ float2 c_mul(float2 a, float2 w) { return make_float2(a.x*w.x - a.y*w.y, a.x*w.y + a.y*w.x); }
__device__ __forceinline__ float2 c_mulc(float2 a, float2 w) { return make_float2(a.x*w.x + a.y*w.y, a.y*w.x - a.x*w.y); }
__device__ __forceinline__ float2 c_nim(float2 a) { return make_float2(a.y, -a.x); }  // -i*a
__device__ __forceinline__ float2 c_pim(float2 a) { return make_float2(-a.y, a.x); }  // +i*a

// forward DIF radix-4 butterfly (twiddles applied after combine)
__device__ __forceinline__ void fwd_r4(float2& a0, float2& a1, float2& a2, float2& a3,
                                       float2 w1, float2 w2, float2 w3) {
    float2 s0 = c_add(a0, a2), s1 = c_sub(a0, a2);
    float2 s2 = c_add(a1, a3), s3 = c_nim(c_sub(a1, a3));
    a0 = c_add(s0, s2);
    a1 = c_mul(c_add(s1, s3), w1);
    a2 = c_mul(c_sub(s0, s2), w2);
    a3 = c_mul(c_sub(s1, s3), w3);
}
// inverse DIT radix-4 butterfly (conjugate twiddles applied before combine)
__device__ __forceinline__ void inv_r4(float2& a0, float2& a1, float2& a2, float2& a3,
                                       float2 w1, float2 w2, float2 w3) {
    float2 b1 = c_mulc(a1, w1), b2 = c_mulc(a2, w2), b3 = c_mulc(a3, w3);
    float2 u0 = c_add(a0, b2), u1 = c_sub(a0, b2);
    float2 u2 = c_add(b1, b3), u3 = c_pim(c_sub(b1, b3));
    a0 = c_add(u0, u2); a1 = c_add(u1, u3);
    a2 = c_sub(u0, u2); a3 = c_sub(u1, u3);
}

__global__ __launch_bounds__(NT) void hwtv_kernel(
    const float* __restrict__ Yg,
    const float* __restrict__ Wg,
    float* __restrict__ outg,
    float* __restrict__ wsg)
{
    extern __shared__ char smem[];
    float2* C   = (float2*)smem;                             // 128 x 132 float2
    float2* TW  = (float2*)(smem + 135168);                  // 128 twiddles W_128^k
    float*  D1s = (float*)(smem + 135168 + 1024);            // 128 slot-indexed 4sin^2

    const int tid = threadIdx.x;
    const size_t base  = (size_t)blockIdx.x * NPIX;
    const float* Y  = Yg + base;
    const float* Wt = Wg + base;
    float* out = outg + base;
    const size_t plane = (size_t)NIMG * NPIX;
    float* ag  = wsg + base;            // a = mu1*X + G1
    float* g1g = wsg + plane + base;    // G1

    // ---- one-time tables ----
    if (tid < 128) {
        float ang = -2.0f * PI_F * (float)tid / 128.0f;
        TW[tid] = make_float2(cosf(ang), sinf(ang));
        // mixed-radix digit-reversal slot for stages R4,R4,R4,R2:
        int k = tid;
        int slot = ((k & 3) << 5) | (((k >> 2) & 3) << 3) | (((k >> 4) & 3) << 1) | (k >> 6);
        float s = sinf(PI_F * (float)k / 128.0f);
        D1s[slot] = 4.0f * s * s;
    }
    float bh[PXT], bv[PXT];   // ONLY persistent register state (32 VGPRs)
    #pragma unroll
    for (int k = 0; k < PXT; ++k) {
        int p = tid + k * NT;
        float y = Y[p];
        C[IDX(p)] = make_float2(y, 0.0f);  // Z0 = Y
        ag[p]  = 0.1f * y;                 // mu1*X0 + G1_0 = mu1*Y
        g1g[p] = 0.0f;
        bh[k] = 0.0f;
        bv[k] = 0.0f;
    }
    __syncthreads();

    float mu1 = 0.1f, mu2 = 0.1f;

    for (int it = 0; it < N_ITE; ++it) {
        const float mu2p   = mu2 * (1.0f / RHO_F);
        const float inv_m2 = 1.0f / mu2;
        const float thr    = LAM_F * inv_m2;

        // ---- P1: shrink; bh = mu2*Uh + G21, bv = mu2*Uv + G22 ----
        #pragma unroll
        for (int k = 0; k < PXT; ++k) {
            int p    = tid + k * NT;
            int col  = p & 127;
            int rowb = p & ~127;
            float z  = C[IDX(p)].x;
            float zl = C[IDX(rowb | ((col + 127) & 127))].x;
            float zu = C[IDX((p + NPIX - NSIDE) & (NPIX - 1))].x;
            float dhz = z - zl;
            float dvz = z - zu;
            float g21 = (it == 0) ? 0.0f : fmaf(-mu2p, dhz, bh[k]);
            float g22 = (it == 0) ? 0.0f : fmaf(-mu2p, dvz, bv[k]);
            float ah = dhz - g21 * inv_m2;
            float av = dvz - g22 * inv_m2;
            float uh = copysignf(fmaxf(fabsf(ah) - thr, 0.0f), ah);
            float uv = copysignf(fmaxf(fabsf(av) - thr, 0.0f), av);
            bh[k] = fmaf(mu2, uh, g21);
            bv[k] = fmaf(mu2, uv, g22);
        }
        __syncthreads();

        // ---- P2: stage (bh, bv) in C for neighbor exchange ----
        #pragma unroll
        for (int k = 0; k < PXT; ++k) {
            int p = tid + k * NT;
            C[IDX(p)] = make_float2(bh[k], bv[k]);
        }
        __syncthreads();

        // ---- P3: numerator = a + Dh^T bh + Dv^T bv, two 8-px chunks ----
        {
            float numv[8];
            float bvd15 = C[IDX(((tid + 15 * NT) + NSIDE) & (NPIX - 1))].y;
            #pragma unroll
            for (int k = 0; k < 8; ++k) {
                int p    = tid + k * NT;
                int col  = p & 127;
                int rowb = p & ~127;
                float bhr = C[IDX(rowb | ((col + 1) & 127))].x;
                float bvd = C[IDX(p + NSIDE)].y;
                numv[k] = ag[p] + (bh[k] - bhr) + (bv[k] - bvd);
            }
            __syncthreads();
            #pragma unroll
            for (int k = 0; k < 8; ++k) {
                int p = tid + k * NT;
                C[IDX(p)] = make_float2(numv[k], 0.0f);
            }
            __syncthreads();
            #pragma unroll
            for (int k = 8; k < PXT; ++k) {
                int p    = tid + k * NT;
                int col  = p & 127;
                int rowb = p & ~127;
                float bhr = C[IDX(rowb | ((col + 1) & 127))].x;
                float bvd = (p + NSIDE < NPIX) ? C[IDX(p + NSIDE)].y : bvd15;
                numv[k - 8] = ag[p] + (bh[k] - bhr) + (bv[k] - bvd);
            }
            __syncthreads();
            #pragma unroll
            for (int k = 8; k < PXT; ++k) {
                int p = tid + k * NT;
                C[IDX(p)] = make_float2(numv[k - 8], 0.0f);
            }
            __syncthreads();
        }

        // ================= forward FFT over rows =================
        {
            const int b  = tid & 31;
            const int r0 = tid >> 5;            // 0..31
            {   // R4 len=32: j = b
                float2 w1 = TW[b], w2 = TW[2 * b], w3 = TW[3 * b];
                #pragma unroll 1
                for (int q = 0; q < 4; ++q) {
                    int o = (r0 + (q << 5)) * ROWF2 + b;
                    float2 a0 = C[o], a1 = C[o + 32], a2 = C[o + 64], a3 = C[o + 96];
                    fwd_r4(a0, a1, a2, a3, w1, w2, w3);
                    C[o] = a0; C[o + 32] = a1; C[o + 64] = a2; C[o + 96] = a3;
                }
                __syncthreads();
            }
            {   // R4 len=8
                int j = b & 7, bas = ((b >> 3) << 5) + j;
                float2 w1 = TW[4 * j], w2 = TW[8 * j], w3 = TW[12 * j];
                #pragma unroll 1
                for (int q = 0; q < 4; ++q) {
                    int o = (r0 + (q << 5)) * ROWF2 + bas;
                    float2 a0 = C[o], a1 = C[o + 8], a2 = C[o + 16], a3 = C[o + 24];
                    fwd_r4(a0, a1, a2, a3, w1, w2, w3);
                    C[o] = a0; C[o + 8] = a1; C[o + 16] = a2; C[o + 24] = a3;
                }
                __syncthreads();
            }
            {   // R4 len=2
                int j = b & 1, bas = ((b >> 1) << 3) + j;
                float2 w1 = TW[16 * j], w2 = TW[32 * j], w3 = TW[48 * j];
                #pragma unroll 1
                for (int q = 0; q < 4; ++q) {
                    int o = (r0 + (q << 5)) * ROWF2 + bas;
                    float2 a0 = C[o], a1 = C[o + 2], a2 = C[o + 4], a3 = C[o + 6];
                    fwd_r4(a0, a1, a2, a3, w1, w2, w3);
                    C[o] = a0; C[o + 2] = a1; C[o + 4] = a2; C[o + 6] = a3;
                }
                __syncthreads();
            }
            {   // R2 len=1: adjacent pairs as float4 (conflict-free)
                float4* C4 = (float4*)C;
                const int t = tid & 63, s0r = tid >> 6;  // 0..15
                #pragma unroll 2
                for (int q = 0; q < 8; ++q) {
                    int o = (s0r + (q << 4)) * 66 + t;   // 66 float4 per row
                    float4 v = C4[o];
                    C4[o] = make_float4(v.x + v.z, v.y + v.w, v.x - v.z, v.y - v.w);
                }
                __syncthreads();
            }
        }
        // ================= forward FFT over cols =================
        {
            const int c  = tid & 127;
            const int rr = tid >> 7;            // 0..7
            {   // R4 len=32
                #pragma unroll 1
                for (int q = 0; q < 4; ++q) {
                    int b = rr + (q << 3);
                    float2 w1 = TW[b], w2 = TW[2 * b], w3 = TW[3 * b];
                    int o = b * ROWF2 + c;
                    float2 a0 = C[o], a1 = C[o + 32 * ROWF2], a2 = C[o + 64 * ROWF2], a3 = C[o + 96 * ROWF2];
                    fwd_r4(a0, a1, a2, a3, w1, w2, w3);
                    C[o] = a0; C[o + 32 * ROWF2] = a1; C[o + 64 * ROWF2] = a2; C[o + 96 * ROWF2] = a3;
                }
                __syncthreads();
            }
            {   // R4 len=8
                #pragma unroll 1
                for (int q = 0; q < 4; ++q) {
                    int b = rr + (q << 3);
                    int j = b & 7, bas = ((b >> 3) << 5) + j;
                    float2 w1 = TW[4 * j], w2 = TW[8 * j], w3 = TW[12 * j];
                    int o = bas * ROWF2 + c;
                    float2 a0 = C[o], a1 = C[o + 8 * ROWF2], a2 = C[o + 16 * ROWF2], a3 = C[o + 24 * ROWF2];
                    fwd_r4(a0, a1, a2, a3, w1, w2, w3);
                    C[o] = a0; C[o + 8 * ROWF2] = a1; C[o + 16 * ROWF2] = a2; C[o + 24 * ROWF2] = a3;
                }
                __syncthreads();
            }
            {   // R4 len=2
                #pragma unroll 1
                for (int q = 0; q < 4; ++q) {
                    int b = rr + (q << 3);
                    int j = b & 1, bas = ((b >> 1) << 3) + j;
                    float2 w1 = TW[16 * j], w2 = TW[32 * j], w3 = TW[48 * j];
                    int o = bas * ROWF2 + c;
                    float2 a0 = C[o], a1 = C[o + 2 * ROWF2], a2 = C[o + 4 * ROWF2], a3 = C[o + 6 * ROWF2];
                    fwd_r4(a0, a1, a2, a3, w1, w2, w3);
                    C[o] = a0; C[o + 2 * ROWF2] = a1; C[o + 4 * ROWF2] = a2; C[o + 6 * ROWF2] = a3;
                }
                __syncthreads();
            }
            {   // R2 len=1: row pairs (2t, 2t+1)
                #pragma unroll 2
                for (int q = 0; q < 8; ++q) {
                    int t = rr + (q << 3);              // 0..63
                    int o = (t << 1) * ROWF2 + c;
                    float2 A = C[o], B = C[o + ROWF2];
                    C[o] = c_add(A, B); C[o + ROWF2] = c_sub(A, B);
                }
                __syncthreads();
            }
        }

        // ---- pointwise Fourier solve (slot-indexed denom), 1/N^2 folded ----
        {
            const float sc = 1.0f / (float)NPIX;
            #pragma unroll 2
            for (int k = 0; k < PXT; ++k) {
                int p = tid + k * NT;
                int r = p >> 7, c2 = p & 127;
                float den = mu1 + mu2 * (D1s[r] + D1s[c2]);
                float f = sc * __builtin_amdgcn_rcpf(den);
                int o = r * ROWF2 + c2;
                float2 v = C[o];
                C[o] = make_float2(v.x * f, v.y * f);
            }
            __syncthreads();
        }

        // ================= inverse FFT over cols =================
        {
            const int c  = tid & 127;
            const int rr = tid >> 7;
            {   // R2 len=1
                #pragma unroll 2
                for (int q = 0; q < 8; ++q) {
                    int t = rr + (q << 3);
                    int o = (t << 1) * ROWF2 + c;
                    float2 A = C[o], B = C[o + ROWF2];
                    C[o] = c_add(A, B); C[o + ROWF2] = c_sub(A, B);
                }
                __syncthreads();
            }
            {   // R4 len=2
                #pragma unroll 1
                for (int q = 0; q < 4; ++q) {
                    int b = rr + (q << 3);
                    int j = b & 1, bas = ((b >> 1) << 3) + j;
                    float2 w1 = TW[16 * j], w2 = TW[32 * j], w3 = TW[48 * j];
                    int o = bas * ROWF2 + c;
                    float2 a0 = C[o], a1 = C[o + 2 * ROWF2], a2 = C[o + 4 * ROWF2], a3 = C[o + 6 * ROWF2];
                    inv_r4(a0, a1, a2, a3, w1, w2, w3);
                    C[o] = a0; C[o + 2 * ROWF2] = a1; C[o + 4 * ROWF2] = a2; C[o + 6 * ROWF2] = a3;
                }
                __syncthreads();
            }
            {   // R4 len=8
                #pragma unroll 1
                for (int q = 0; q < 4; ++q) {
                    int b = rr + (q << 3);
                    int j = b & 7, bas = ((b >> 3) << 5) + j;
                    float2 w1 = TW[4 * j], w2 = TW[8 * j], w3 = TW[12 * j];
                    int o = bas * ROWF2 + c;
                    float2 a0 = C[o], a1 = C[o + 8 * ROWF2], a2 = C[o + 16 * ROWF2], a3 = C[o + 24 * ROWF2];
                    inv_r4(a0, a1, a2, a3, w1, w2, w3);
                    C[o] = a0; C[o + 8 * ROWF2] = a1; C[o + 16 * ROWF2] = a2; C[o + 24 * ROWF2] = a3;
                }
                __syncthreads();
            }
            {   // R4 len=32
                #pragma unroll 1
                for (int q = 0; q < 4; ++q) {
                    int b = rr + (q << 3);
                    float2 w1 = TW[b], w2 = TW[2 * b], w3 = TW[3 * b];
                    int o = b * ROWF2 + c;
                    float2 a0 = C[o], a1 = C[o + 32 * ROWF2], a2 = C[o + 64 * ROWF2], a3 = C[o + 96 * ROWF2];
                    inv_r4(a0, a1, a2, a3, w1, w2, w3);
                    C[o] = a0; C[o + 32 * ROWF2] = a1; C[o + 64 * ROWF2] = a2; C[o + 96 * ROWF2] = a3;
                }
                __syncthreads();
            }
        }
        // ================= inverse FFT over rows =================
        {
            const int b  = tid & 31;
            const int r0 = tid >> 5;
            {   // R2 len=1 via float4
                float4* C4 = (float4*)C;
                const int t = tid & 63, s0r = tid >> 6;
                #pragma unroll 2
                for (int q = 0; q < 8; ++q) {
                    int o = (s0r + (q << 4)) * 66 + t;
                    float4 v = C4[o];
                    C4[o] = make_float4(v.x + v.z, v.y + v.w, v.x - v.z, v.y - v.w);
                }
                __syncthreads();
            }
            {   // R4 len=2
                int j = b & 1, bas = ((b >> 1) << 3) + j;
                float2 w1 = TW[16 * j], w2 = TW[32 * j], w3 = TW[48 * j];
                #pragma unroll 1
                for (int q = 0; q < 4; ++q) {
                    int o = (r0 + (q << 5)) * ROWF2 + bas;
                    float2 a0 = C[o], a1 = C[o + 2], a2 = C[o + 4], a3 = C[o + 6];
                    inv_r4(a0, a1, a2, a3, w1, w2, w3);
                    C[o] = a0; C[o + 2] = a1; C[o + 4] = a2; C[o + 6] = a3;
                }
                __syncthreads();
            }
            {   // R4 len=8
                int j = b & 7, bas = ((b >> 3) << 5) + j;
                float2 w1 = TW[4 * j], w2 = TW[8 * j], w3 = TW[12 * j];
                #pragma unroll 1
                for (int q = 0; q < 4; ++q) {
                    int o = (r0 + (q << 5)) * ROWF2 + bas;
                    float2 a0 = C[o], a1 = C[o + 8], a2 = C[o + 16], a3 = C[o + 24];
                    inv_r4(a0, a1, a2, a3, w1, w2, w3);
                    C[o] = a0; C[o + 8] = a1; C[o + 16] = a2; C[o + 24] = a3;
                }
                __syncthreads();
            }
            {   // R4 len=32
                float2 w1 = TW[b], w2 = TW[2 * b], w3 = TW[3 * b];
                #pragma unroll 1
                for (int q = 0; q < 4; ++q) {
                    int o = (r0 + (q << 5)) * ROWF2 + b;
                    float2 a0 = C[o], a1 = C[o + 32], a2 = C[o + 64], a3 = C[o + 96];
                    inv_r4(a0, a1, a2, a3, w1, w2, w3);
                    C[o] = a0; C[o + 32] = a1; C[o + 64] = a2; C[o + 96] = a3;
                }
                __syncthreads();
            }
        }

        // ---- Epilogue: X/G1/a update via ws; Z stays in C[].x ----
        const float mu1n = mu1 * RHO_F;
        if (it != N_ITE - 1) {
            #pragma unroll 2
            for (int k = 0; k < PXT; ++k) {
                int p = tid + k * NT;
                float z   = C[IDX(p)].x;
                float g1v = g1g[p];
                float w   = Wt[p];
                float x   = fmaf(w, Y[p], fmaf(mu1, z, -g1v)) *
                            __builtin_amdgcn_rcpf(w + mu1);
                g1v = fmaf(mu1, x - z, g1v);
                g1g[p] = g1v;
                ag[p]  = fmaf(mu1n, x, g1v);
            }
        } else {
            #pragma unroll 2
            for (int k = 0; k < PXT; ++k) {
                int p = tid + k * NT;
                out[p] = C[IDX(p)].x;
            }
        }
        // no barrier: next P1 only reads C (covered by last FFT barrier).

        mu1 *= RHO_F;
        mu2 *= RHO_F;
    }
}

extern "C" void kernel_launch(void* const* d_in, const int* in_sizes, int n_in,
                              void* d_out, int out_size, void* d_ws, size_t ws_size,
                              hipStream_t stream) {
    (void)in_sizes; (void)n_in; (void)out_size; (void)ws_size;
    const float* Y   = (const float*)d_in[0];
    const float* inW = (const float*)d_in[1];
    float* out = (float*)d_out;
    float* ws  = (float*)d_ws;   // needs >= 16.3 MB (a + g1 planes)

    const size_t smem_bytes = 135168 + 1024 + 512;   // C (128x132 f2) + TW + D1s
    hipFuncSetAttribute((const void*)hwtv_kernel,
                        hipFuncAttributeMaxDynamicSharedMemorySize,
                        (int)smem_bytes);
    hipLaunchKernelGGL(hwtv_kernel, dim3(NIMG), dim3(NT), smem_bytes, stream,
                       Y, inW, out, ws);
}